// Round 1
// baseline (25.277 us; speedup 1.0000x reference)
//
#include <hip/hip_runtime.h>
#include <hip/hip_bf16.h>

#define MODEL_DIM 2048
#define F4_PER_ROW (MODEL_DIM / 4)   // 512

__global__ __launch_bounds__(256) void qembed_gather_kernel(
    const float* __restrict__ weights,  // [VOCAB, MODEL_DIM]
    const float* __restrict__ scales,   // [VOCAB]
    const int*   __restrict__ tokens,   // [N_TOKENS]
    float* __restrict__ out)            // [N_TOKENS, MODEL_DIM]
{
    const int t   = blockIdx.x;                 // token index
    const int tok = tokens[t];
    const float s = scales[tok];

    const float4* __restrict__ wrow =
        reinterpret_cast<const float4*>(weights + (size_t)tok * MODEL_DIM);
    float4* __restrict__ orow =
        reinterpret_cast<float4*>(out + (size_t)t * MODEL_DIM);

    // 512 float4 per row, 256 threads -> 2 iterations each, fully coalesced.
    #pragma unroll
    for (int i = threadIdx.x; i < F4_PER_ROW; i += 256) {
        float4 v = wrow[i];
        float4 r;
        // jnp.round == round-half-to-even == rintf (default rounding mode)
        r.x = fminf(fmaxf(rintf(v.x), -128.0f), 127.0f) * s;
        r.y = fminf(fmaxf(rintf(v.y), -128.0f), 127.0f) * s;
        r.z = fminf(fmaxf(rintf(v.z), -128.0f), 127.0f) * s;
        r.w = fminf(fmaxf(rintf(v.w), -128.0f), 127.0f) * s;
        orow[i] = r;
    }
}

extern "C" void kernel_launch(void* const* d_in, const int* in_sizes, int n_in,
                              void* d_out, int out_size, void* d_ws, size_t ws_size,
                              hipStream_t stream) {
    const float* weights = (const float*)d_in[0];
    const float* scales  = (const float*)d_in[1];
    const int*   tokens  = (const int*)d_in[2];
    float* out = (float*)d_out;

    const int n_tokens = in_sizes[2];           // 8192

    qembed_gather_kernel<<<n_tokens, 256, 0, stream>>>(weights, scales, tokens, out);
}